// Round 11
// baseline (113.458 us; speedup 1.0000x reference)
//
#include <hip/hip_runtime.h>
#include <math.h>

// Problem constants
#define DD 256
#define HH 8
#define AA 32
#define SS 512
#define BB 2
constexpr float BCONST      = 0.9f;
constexpr float ONE_MINUS_B = 0.1f;
constexpr float EPSF        = 1e-10f;
constexpr float SCALEF      = 0.0625f;   // 1/sqrt(256), exact power of 2
constexpr float FLTMAX      = 3.402823466e38f;

// Workspace layout (float offsets)
#define OFF_QKV    0
#define OFF_VP     786432
#define OFF_EW     1048576
#define OFF_PMIN   1310720
#define OFF_PMAX   1318912
#define OFF_VMIN   1327104
#define OFF_VRANGE 1327616
#define OFF_P      1328128

// Swizzled chunk buffer: row-major LD=32 floats, bank-quad ^= (row>>2)&7.
#define KB4(buf, row, col4) \
  (&(buf)[((row) << 5) | ((((col4) >> 2) ^ (((row) >> 2) & 7)) << 2)])

// ---------------------------------------------------------------------------
// Tiled fp32 GEMM with PER-ROW B-source selection (tiles may straddle the
// W_Q | W_KV boundary): Brow(j) = j < nsplit ? B0 + j*K : B1 + (j-nsplit)*K.
// QKV: TM=64/TN=48/RM=4/RN=3 -> grid 16x16 = 256 blocks (1/CU, even),
// 7 b128 per 48 FMA = 0.146/FMA (R9's 32x64 was 0.1875 at 1.5 blocks/CU,
// R10's 64x64 was 0.125 but only 192 blocks -> 64 idle CUs).
// MM=true: V columns (j>=512) get per-row-tile min/max partials
// pminP/pmaxP[i0/TM][d] (8 tiles per batch at TM=64).
// ---------------------------------------------------------------------------
template<int TM, int TN, int RM, int RN, bool MM>
__global__ __launch_bounds__(256) void gemm_t(
    const float* __restrict__ A, const float* __restrict__ B0,
    const float* __restrict__ B1, int nsplit,
    float* __restrict__ C, int ldc, int K, int lda,
    float* __restrict__ pminP, float* __restrict__ pmaxP) {
  constexpr int LDT = 36;
  constexpr int CG  = TN / RN;         // col groups (16)
  constexpr int UA  = (TM * 8 + 255) / 256;   // A f4-chunks per thread
  constexpr int UB  = (TN * 8 + 255) / 256;   // B f4-chunks per thread
  constexpr int BG  = TN * 8 - 256;           // B chunk-1 guard (t < BG)
  __shared__ float As[TM][LDT];
  __shared__ float Bs[TN][LDT];
  const int i0 = blockIdx.x * TM;
  const int j0 = blockIdx.y * TN;
  const int t  = threadIdx.x;
  const int aro = t >> 3;              // staging row 0..31 (chunk t)
  const int aco = (t & 7) << 2;        // staging col 0,4,..,28
  const int tx = t % CG, ty = t / CG;

  // per-row B pointers (uniform per staged row)
  const int jb0 = j0 + aro;
  const float* brow0 = (jb0 < nsplit) ? (B0 + (size_t)jb0 * K)
                                      : (B1 + (size_t)(jb0 - nsplit) * K);
  const int jb1 = j0 + aro + 32;
  const float* brow1 = (jb1 < nsplit) ? (B0 + (size_t)jb1 * K)
                                      : (B1 + (size_t)(jb1 - nsplit) * K);

  float4 pa[UA], pb[UB];
  pa[0] = *(const float4*)(A + (size_t)(i0 + aro) * lda + aco);
  if constexpr (UA == 2)
    pa[1] = *(const float4*)(A + (size_t)(i0 + aro + 32) * lda + aco);
  pb[0] = *(const float4*)(brow0 + aco);
  if constexpr (UB == 2)
    if (t < BG) pb[1] = *(const float4*)(brow1 + aco);

  float acc[RM][RN] = {};
  for (int k0 = 0; k0 < K; k0 += 32) {
    __syncthreads();                   // previous iteration's LDS reads done
    *(float4*)&As[aro][aco] = pa[0];
    if constexpr (UA == 2) *(float4*)&As[aro + 32][aco] = pa[1];
    *(float4*)&Bs[aro][aco] = pb[0];
    if constexpr (UB == 2)
      if (t < BG) *(float4*)&Bs[aro + 32][aco] = pb[1];
    __syncthreads();
    if (k0 + 32 < K) {                 // prefetch next K-step
      pa[0] = *(const float4*)(A + (size_t)(i0 + aro) * lda + k0 + 32 + aco);
      if constexpr (UA == 2)
        pa[1] = *(const float4*)(A + (size_t)(i0 + aro + 32) * lda + k0 + 32 + aco);
      pb[0] = *(const float4*)(brow0 + k0 + 32 + aco);
      if constexpr (UB == 2)
        if (t < BG) pb[1] = *(const float4*)(brow1 + k0 + 32 + aco);
    }
#pragma unroll
    for (int kk = 0; kk < 32; kk += 4) {
      float4 af[RM], bf[RN];
#pragma unroll
      for (int r = 0; r < RM; ++r) af[r] = *(const float4*)&As[ty * RM + r][kk];
#pragma unroll
      for (int c = 0; c < RN; ++c) bf[c] = *(const float4*)&Bs[tx + CG * c][kk];
#pragma unroll
      for (int r = 0; r < RM; ++r)
#pragma unroll
        for (int c = 0; c < RN; ++c)
          acc[r][c] += af[r].x * bf[c].x + af[r].y * bf[c].y +
                       af[r].z * bf[c].z + af[r].w * bf[c].w;
    }
  }
#pragma unroll
  for (int r = 0; r < RM; ++r)
#pragma unroll
    for (int c = 0; c < RN; ++c)
      C[(size_t)(i0 + ty * RM + r) * ldc + j0 + tx + CG * c] = acc[r][c];

  if (MM && j0 + TN > 512) {           // tile contains V columns
    __syncthreads();                   // main-loop As/Bs reads done
    float* mnb = &As[0][0];            // [TN cols][17]
    float* mxb = &Bs[0][0];
#pragma unroll
    for (int c = 0; c < RN; ++c) {
      float mn = acc[0][c], mx = acc[0][c];
#pragma unroll
      for (int r = 1; r < RM; ++r) {
        mn = fminf(mn, acc[r][c]);
        mx = fmaxf(mx, acc[r][c]);
      }
      mnb[(tx + CG * c) * 17 + ty] = mn;
      mxb[(tx + CG * c) * 17 + ty] = mx;
    }
    __syncthreads();
    if (t < TN && j0 + t >= 512) {     // per-column straddle guard
      float mn = mnb[t * 17], mx = mxb[t * 17];
#pragma unroll
      for (int i = 1; i < 16; ++i) {
        mn = fminf(mn, mnb[t * 17 + i]);
        mx = fmaxf(mx, mxb[t * 17 + i]);
      }
      const int bx = i0 / TM;          // row-tile (8 per batch @ TM=64)
      pminP[bx * 256 + (j0 + t - 512)] = mn;
      pmaxP[bx * 256 + (j0 + t - 512)] = mx;
    }
  }
}

// ---------------------------------------------------------------------------
// vp = expm1(p * log(v_norm)); also vmin / vrange per (b,d) and pw.
// 8 row-tile partials per batch (TM=64 in QKV).
// ---------------------------------------------------------------------------
__global__ __launch_bounds__(256) void vpk(
    const float* __restrict__ qkv, const float* __restrict__ pminP,
    const float* __restrict__ pmaxP, const float* __restrict__ p_param,
    float* __restrict__ vp, float* __restrict__ vminw,
    float* __restrict__ vrangew, float* __restrict__ pw) {
  const int blk = blockIdx.x;           // 0..1023
  const int b = blk >> 9, s = blk & 511;
  const int d = threadIdx.x;
  float mn = pminP[(b * 8) * 256 + d];
  float mx = pmaxP[(b * 8) * 256 + d];
#pragma unroll
  for (int c = 1; c < 8; ++c) {
    mn = fminf(mn, pminP[(b * 8 + c) * 256 + d]);
    mx = fmaxf(mx, pmaxP[(b * 8 + c) * 256 + d]);
  }
  float p = 50000.0f * tanhf(0.005f * p_param[d]) + 1.0f;
  if (p == 0.0f) p = 0.0001f;
  const float range = mx - mn + EPSF;
  const float v  = qkv[((size_t)(b * 512 + s)) * 768 + 512 + d];
  const float vn = (ONE_MINUS_B * (v - mn)) / range + BCONST;
  vp[(size_t)blk * 256 + d] = expm1f(p * logf(vn));
  if (s == 0) { vminw[b * 256 + d] = mn; vrangew[b * 256 + d] = range; }
  if (blk == 0) pw[d] = p;
}

// ---------------------------------------------------------------------------
// Fused attention v4: R9 structure (32q/block, full 512-k panel, LDS-lean
// 8qx8k / 8qx4a micro-tiles) with softmax FOLDED INTO PHASE 1:
//  - no max subtraction (scores sigma~0.35, |s|<~3; fp32 exp overflows at 88
//    -> 40-sigma margin; exp(s)/T identical mathematically)
//  - __expf applied to the 8x8 score block in registers; row sums reduced by
//    wave butterfly (each q-row lives entirely in one wave: qgw = wave id);
//    unnormalized e written to sc. Deletes the phase-2 LDS sweep + 3 barriers.
// grid = (S/32, B*H); 256 threads; 1 block/CU.
// ---------------------------------------------------------------------------
__global__ __launch_bounds__(256) void attn_k(
    const float* __restrict__ qkv, const float* __restrict__ vp,
    const float* __restrict__ pw, const float* __restrict__ vminw,
    const float* __restrict__ vrangew, float* __restrict__ ew) {
  __shared__ float qs[32][36];
  __shared__ float sc[32 * 516];       // [q][k] unnormalized softmax e
  __shared__ float kb[512 * 32];       // swizzled K / VP panel (reused: part)
  __shared__ float red[32];            // per-row sum T
  const int bh  = blockIdx.y;
  const int b   = bh >> 3, h = bh & 7;
  const int q0g = blockIdx.x * 32;
  const int t   = threadIdx.x;
  const int srow = t >> 3, scol4 = (t & 7) << 2;

  // q tile (32 x 32), fold in SCALE (exact *2^-4)
  {
    const int q = t >> 3, c4 = (t & 7) << 2;
    float4 qv = *(const float4*)(qkv + ((size_t)(b * 512 + q0g + q)) * 768 + h * 32 + c4);
    qv.x *= SCALEF; qv.y *= SCALEF; qv.z *= SCALEF; qv.w *= SCALEF;
    *(float4*)&qs[q][c4] = qv;
  }
  // stage FULL K panel (512 rows)
#pragma unroll 8
  for (int u = 0; u < 16; ++u) {
    const int r = srow + 32 * u;
    float4 v = *(const float4*)(qkv + ((size_t)(b * 512 + r)) * 768 + 256 + h * 32 + scol4);
    *(float4*)KB4(kb, r, scol4) = v;
  }
  __syncthreads();

  // ---- Phase 1: scores + inline softmax. thread = 8q (qgw+4r) x 8k.
  {
    const int qgw = t >> 6;            // wave id: wave-uniform q group
    const int kg  = t & 63;            // k cols kg*4..+3 and 256+kg*4..+3
    float s8[8][8] = {};
#pragma unroll 2
    for (int kk = 0; kk < 32; kk += 4) {
      float4 qf[8], kf1[4], kf2[4];
#pragma unroll
      for (int r = 0; r < 8; ++r) qf[r] = *(const float4*)&qs[qgw + 4 * r][kk];
#pragma unroll
      for (int c = 0; c < 4; ++c) {
        kf1[c] = *(const float4*)KB4(kb, kg * 4 + c, kk);
        kf2[c] = *(const float4*)KB4(kb, 256 + kg * 4 + c, kk);
      }
#pragma unroll
      for (int r = 0; r < 8; ++r)
#pragma unroll
        for (int c = 0; c < 4; ++c) {
          s8[r][c]     += qf[r].x * kf1[c].x + qf[r].y * kf1[c].y +
                          qf[r].z * kf1[c].z + qf[r].w * kf1[c].w;
          s8[r][4 + c] += qf[r].x * kf2[c].x + qf[r].y * kf2[c].y +
                          qf[r].z * kf2[c].z + qf[r].w * kf2[c].w;
        }
    }
    // exp in registers + per-row local sums
    float rs[8];
#pragma unroll
    for (int r = 0; r < 8; ++r) {
      float s = 0.f;
#pragma unroll
      for (int c = 0; c < 8; ++c) {
        s8[r][c] = __expf(s8[r][c]);
        s += s8[r][c];
      }
      rs[r] = s;
    }
    // wave butterfly: full row sums (row qgw+4r owned entirely by wave qgw)
#pragma unroll
    for (int m = 1; m < 64; m <<= 1)
#pragma unroll
      for (int r = 0; r < 8; ++r) rs[r] += __shfl_xor(rs[r], m);
    if ((t & 63) == 0)
#pragma unroll
      for (int r = 0; r < 8; ++r) red[qgw + 4 * r] = rs[r];
    // write unnormalized e
#pragma unroll
    for (int r = 0; r < 8; ++r) {
      const int rq = qgw + 4 * r;
      *(float4*)&sc[rq * 516 + kg * 4] =
          make_float4(s8[r][0], s8[r][1], s8[r][2], s8[r][3]);
      *(float4*)&sc[rq * 516 + 256 + kg * 4] =
          make_float4(s8[r][4], s8[r][5], s8[r][6], s8[r][7]);
    }
  }
  __syncthreads();                     // sc/red done; kb K-reads done

  // ---- stage FULL VP panel into kb
#pragma unroll 8
  for (int u = 0; u < 16; ++u) {
    const int r = srow + 32 * u;
    float4 v = *(const float4*)(vp + ((size_t)(b * 512 + r)) * 256 + h * 32 + scol4);
    *(float4*)KB4(kb, r, scol4) = v;
  }
  __syncthreads();

  // ---- Phase 3: ACC[q][a] = sum_k e[q][k]*vp[k][a]; thread = 8q x 4a,
  // 8-way k-split (64 k per slice).
  const int ag  = t & 7;               // a cols ag*4..+3
  const int qg3 = (t >> 3) & 3;        // q rows qg3+4r
  const int ks  = t >> 5;              // 0..7
  float a3[8][4] = {};
#pragma unroll 2
  for (int g = 0; g < 16; ++g) {
    const int kbase = ks * 64 + g * 4;
    float4 sq[8], vf[4];
#pragma unroll
    for (int r = 0; r < 8; ++r)
      sq[r] = *(const float4*)&sc[(qg3 + 4 * r) * 516 + kbase];
#pragma unroll
    for (int c = 0; c < 4; ++c)
      vf[c] = *(const float4*)KB4(kb, kbase + c, ag * 4);
#pragma unroll
    for (int r = 0; r < 8; ++r) {
      a3[r][0] += sq[r].x * vf[0].x + sq[r].y * vf[1].x + sq[r].z * vf[2].x + sq[r].w * vf[3].x;
      a3[r][1] += sq[r].x * vf[0].y + sq[r].y * vf[1].y + sq[r].z * vf[2].y + sq[r].w * vf[3].y;
      a3[r][2] += sq[r].x * vf[0].z + sq[r].y * vf[1].z + sq[r].z * vf[2].z + sq[r].w * vf[3].z;
      a3[r][3] += sq[r].x * vf[0].w + sq[r].y * vf[1].w + sq[r].z * vf[2].w + sq[r].w * vf[3].w;
    }
  }

  // ---- fold ks pair within wave (wave w holds ks = 2w, 2w+1)
#pragma unroll
  for (int r = 0; r < 8; ++r)
#pragma unroll
    for (int c = 0; c < 4; ++c)
      a3[r][c] += __shfl_xor(a3[r][c], 32);
  __syncthreads();                     // kb reads done; reuse as part
  float* part = &kb[0];                // [w4][32*36]
  if ((t & 32) == 0) {
    const int w = t >> 6;
#pragma unroll
    for (int r = 0; r < 8; ++r)
#pragma unroll
      for (int c = 0; c < 4; ++c)
        part[w * 1152 + (qg3 + 4 * r) * 36 + ag * 4 + c] = a3[r][c];
  }
  __syncthreads();

  // ---- final 4-wave reduction + robust power-mean epilogue (4 outputs/thr)
  {
    const int q = t >> 3, a0 = (t & 7) << 2;
    const int d0 = h * 32 + a0;
    const float invT = 1.0f / red[q];
    float4 s0 = *(const float4*)&part[q * 36 + a0];
    float4 s1 = *(const float4*)&part[1152 + q * 36 + a0];
    float4 s2 = *(const float4*)&part[2304 + q * 36 + a0];
    float4 s3 = *(const float4*)&part[3456 + q * 36 + a0];
    const float4 pp = *(const float4*)(pw + d0);
    const float4 vr = *(const float4*)(vrangew + b * 256 + d0);
    const float4 vm = *(const float4*)(vminw + b * 256 + d0);
    float4 o;
    o.x = (expf(log1pf((s0.x + s1.x + s2.x + s3.x) * invT) / pp.x) - BCONST) * vr.x / ONE_MINUS_B + vm.x;
    o.y = (expf(log1pf((s0.y + s1.y + s2.y + s3.y) * invT) / pp.y) - BCONST) * vr.y / ONE_MINUS_B + vm.y;
    o.z = (expf(log1pf((s0.z + s1.z + s2.z + s3.z) * invT) / pp.z) - BCONST) * vr.z / ONE_MINUS_B + vm.z;
    o.w = (expf(log1pf((s0.w + s1.w + s2.w + s3.w) * invT) / pp.w) - BCONST) * vr.w / ONE_MINUS_B + vm.w;
    *(float4*)(ew + ((size_t)(b * 512 + q0g + q)) * 256 + d0) = o;
  }
}

// ---------------------------------------------------------------------------
extern "C" void kernel_launch(void* const* d_in, const int* in_sizes, int n_in,
                              void* d_out, int out_size, void* d_ws, size_t ws_size,
                              hipStream_t stream) {
  const float* ctx  = (const float*)d_in[0];
  const float* WQ   = (const float*)d_in[1];
  const float* WKV  = (const float*)d_in[2];
  const float* WOUT = (const float*)d_in[3];
  const float* PP   = (const float*)d_in[4];
  float* ws      = (float*)d_ws;
  float* qkv     = ws + OFF_QKV;
  float* vp      = ws + OFF_VP;
  float* ew      = ws + OFF_EW;
  float* pminP   = ws + OFF_PMIN;
  float* pmaxP   = ws + OFF_PMAX;
  float* vminw   = ws + OFF_VMIN;
  float* vrangew = ws + OFF_VRANGE;
  float* pw      = ws + OFF_P;
  float* out     = (float*)d_out;

  // Fused Q|K|V projection + V min/max partials: 64x48 tiles, 256 blocks
  gemm_t<64, 48, 4, 3, true><<<dim3(16, 16), 256, 0, stream>>>(
      ctx, WQ, WKV, 256, qkv, 768, 256, 256, pminP, pmaxP);
  // expm1(p * log(v_norm)) + p vector + vmin/vrange (8 partials/batch)
  vpk<<<1024, 256, 0, stream>>>(qkv, pminP, pmaxP, PP, vp, vminw, vrangew, pw);
  // Fused attention + inline softmax + power-mean epilogue
  attn_k<<<dim3(16, 16), 256, 0, stream>>>(qkv, vp, pw, vminw, vrangew, ew);
  // Output projection: 1024x256x256, 32x32 tiles (256 blocks)
  gemm_t<32, 32, 2, 2, false><<<dim3(32, 8), 256, 0, stream>>>(
      ew, WOUT, WOUT, 1 << 30, out, 256, 256, 256, nullptr, nullptr);
}

// Round 12
// 107.560 us; speedup vs baseline: 1.0548x; 1.0548x over previous
//
#include <hip/hip_runtime.h>
#include <math.h>

// Problem constants
#define DD 256
#define HH 8
#define AA 32
#define SS 512
#define BB 2
constexpr float BCONST      = 0.9f;
constexpr float ONE_MINUS_B = 0.1f;
constexpr float EPSF        = 1e-10f;
constexpr float SCALEF      = 0.0625f;   // 1/sqrt(256), exact power of 2
constexpr float FLTMAX      = 3.402823466e38f;

// Workspace layout (float offsets)
#define OFF_QKV    0
#define OFF_VP     786432
#define OFF_EW     1048576
#define OFF_PMIN   1310720
#define OFF_PMAX   1318912
#define OFF_VMIN   1327104
#define OFF_VRANGE 1327616
#define OFF_P      1328128

// Swizzled chunk buffer: row-major LD=32 floats, bank-quad ^= (row>>2)&7.
#define KB4(buf, row, col4) \
  (&(buf)[((row) << 5) | ((((col4) >> 2) ^ (((row) >> 2) & 7)) << 2)])

// ---------------------------------------------------------------------------
// Tiled fp32 GEMM (R9 config — empirical best of the family across
// R9/R10/R11): C[i][j] = dot(A[i,:K], Brow(j)).
// MM=true: V-column blocks also write per-row-tile min/max partials.
// ---------------------------------------------------------------------------
template<int TM, int TN, int RM, int RN, bool MM>
__global__ __launch_bounds__(256) void gemm_t(
    const float* __restrict__ A, const float* __restrict__ B0,
    const float* __restrict__ B1, int nsplit,
    float* __restrict__ C, int ldc, int K, int lda,
    float* __restrict__ pminP, float* __restrict__ pmaxP) {
  constexpr int LDT = 36;
  constexpr int CG  = TN / RN;
  constexpr int NA  = TM * 32 / 1024;
  constexpr int NB  = TN * 32 / 1024;
  __shared__ float As[TM][LDT];
  __shared__ float Bs[TN][LDT];
  const int i0 = blockIdx.x * TM;
  const int j0 = blockIdx.y * TN;
  const float* Bsrc = (j0 < nsplit) ? (B0 + (size_t)j0 * K)
                                    : (B1 + (size_t)(j0 - nsplit) * K);
  const int t  = threadIdx.x;
  const int lr = t >> 3;
  const int lc = (t & 7) << 2;
  const int tx = t % CG, ty = t / CG;

  float4 pa[NA], pb[NB];
#pragma unroll
  for (int u = 0; u < NA; ++u)
    pa[u] = *(const float4*)(A + (size_t)(i0 + lr + 32 * u) * lda + lc);
#pragma unroll
  for (int u = 0; u < NB; ++u)
    pb[u] = *(const float4*)(Bsrc + (size_t)(lr + 32 * u) * K + lc);

  float acc[RM][RN] = {};
  for (int k0 = 0; k0 < K; k0 += 32) {
    __syncthreads();
#pragma unroll
    for (int u = 0; u < NA; ++u) *(float4*)&As[lr + 32 * u][lc] = pa[u];
#pragma unroll
    for (int u = 0; u < NB; ++u) *(float4*)&Bs[lr + 32 * u][lc] = pb[u];
    __syncthreads();
    if (k0 + 32 < K) {
#pragma unroll
      for (int u = 0; u < NA; ++u)
        pa[u] = *(const float4*)(A + (size_t)(i0 + lr + 32 * u) * lda + k0 + 32 + lc);
#pragma unroll
      for (int u = 0; u < NB; ++u)
        pb[u] = *(const float4*)(Bsrc + (size_t)(lr + 32 * u) * K + k0 + 32 + lc);
    }
#pragma unroll
    for (int kk = 0; kk < 32; kk += 4) {
      float4 af[RM], bf[RN];
#pragma unroll
      for (int r = 0; r < RM; ++r) af[r] = *(const float4*)&As[ty * RM + r][kk];
#pragma unroll
      for (int c = 0; c < RN; ++c) bf[c] = *(const float4*)&Bs[tx + CG * c][kk];
#pragma unroll
      for (int r = 0; r < RM; ++r)
#pragma unroll
        for (int c = 0; c < RN; ++c)
          acc[r][c] += af[r].x * bf[c].x + af[r].y * bf[c].y +
                       af[r].z * bf[c].z + af[r].w * bf[c].w;
    }
  }
#pragma unroll
  for (int r = 0; r < RM; ++r)
#pragma unroll
    for (int c = 0; c < RN; ++c)
      C[(size_t)(i0 + ty * RM + r) * ldc + j0 + tx + CG * c] = acc[r][c];

  if (MM && j0 >= 512) {
    __syncthreads();
    float* mnb = &As[0][0];
    float* mxb = &Bs[0][0];
#pragma unroll
    for (int c = 0; c < RN; ++c) {
      float mn = acc[0][c], mx = acc[0][c];
#pragma unroll
      for (int r = 1; r < RM; ++r) {
        mn = fminf(mn, acc[r][c]);
        mx = fmaxf(mx, acc[r][c]);
      }
      mnb[(tx + CG * c) * 17 + ty] = mn;
      mxb[(tx + CG * c) * 17 + ty] = mx;
    }
    __syncthreads();
    if (t < TN) {
      float mn = mnb[t * 17], mx = mxb[t * 17];
#pragma unroll
      for (int i = 1; i < 16; ++i) {
        mn = fminf(mn, mnb[t * 17 + i]);
        mx = fmaxf(mx, mxb[t * 17 + i]);
      }
      const int bx = i0 >> 5;          // row-tile 0..31 (16 per batch @ TM=32)
      pminP[bx * 256 + (j0 - 512) + t] = mn;
      pmaxP[bx * 256 + (j0 - 512) + t] = mx;
    }
  }
}

// ---------------------------------------------------------------------------
// vp = expm1(p * log(v_norm)); also vmin / vrange per (b,d) and pw.
// 16 row-tile partials per batch (TM=32 in QKV).
// ---------------------------------------------------------------------------
__global__ __launch_bounds__(256) void vpk(
    const float* __restrict__ qkv, const float* __restrict__ pminP,
    const float* __restrict__ pmaxP, const float* __restrict__ p_param,
    float* __restrict__ vp, float* __restrict__ vminw,
    float* __restrict__ vrangew, float* __restrict__ pw) {
  const int blk = blockIdx.x;           // 0..1023
  const int b = blk >> 9, s = blk & 511;
  const int d = threadIdx.x;
  float mn = pminP[(b * 16) * 256 + d];
  float mx = pmaxP[(b * 16) * 256 + d];
#pragma unroll
  for (int c = 1; c < 16; ++c) {
    mn = fminf(mn, pminP[(b * 16 + c) * 256 + d]);
    mx = fmaxf(mx, pmaxP[(b * 16 + c) * 256 + d]);
  }
  float p = 50000.0f * tanhf(0.005f * p_param[d]) + 1.0f;
  if (p == 0.0f) p = 0.0001f;
  const float range = mx - mn + EPSF;
  const float v  = qkv[((size_t)(b * 512 + s)) * 768 + 512 + d];
  const float vn = (ONE_MINUS_B * (v - mn)) / range + BCONST;
  vp[(size_t)blk * 256 + d] = expm1f(p * logf(vn));
  if (s == 0) { vminw[b * 256 + d] = mn; vrangew[b * 256 + d] = range; }
  if (blk == 0) pw[d] = p;
}

// ---------------------------------------------------------------------------
// Fused attention: R9 structure (32q/block, full 512-k panel, LDS-lean
// 8qx8k / 8qx4a micro-tiles) + inline softmax (the ONLY change vs R9):
// no max subtraction (scores |s| < ~3; fp32 exp overflow at 88 -> huge
// margin; exp(s)/T mathematically identical), __expf on the 8x8 register
// block, wave-butterfly row sums (each q-row lives wholly in wave qgw).
// Deletes the phase-2 LDS sweep + 3 barriers. grid = (S/32, B*H).
// ---------------------------------------------------------------------------
__global__ __launch_bounds__(256) void attn_k(
    const float* __restrict__ qkv, const float* __restrict__ vp,
    const float* __restrict__ pw, const float* __restrict__ vminw,
    const float* __restrict__ vrangew, float* __restrict__ ew) {
  __shared__ float qs[32][36];
  __shared__ float sc[32 * 516];       // [q][k] unnormalized softmax e
  __shared__ float kb[512 * 32];       // swizzled K / VP panel (reused: part)
  __shared__ float red[32];            // per-row sum T
  const int bh  = blockIdx.y;
  const int b   = bh >> 3, h = bh & 7;
  const int q0g = blockIdx.x * 32;
  const int t   = threadIdx.x;
  const int srow = t >> 3, scol4 = (t & 7) << 2;

  // q tile (32 x 32), fold in SCALE (exact *2^-4)
  {
    const int q = t >> 3, c4 = (t & 7) << 2;
    float4 qv = *(const float4*)(qkv + ((size_t)(b * 512 + q0g + q)) * 768 + h * 32 + c4);
    qv.x *= SCALEF; qv.y *= SCALEF; qv.z *= SCALEF; qv.w *= SCALEF;
    *(float4*)&qs[q][c4] = qv;
  }
  // stage FULL K panel (512 rows)
#pragma unroll 8
  for (int u = 0; u < 16; ++u) {
    const int r = srow + 32 * u;
    float4 v = *(const float4*)(qkv + ((size_t)(b * 512 + r)) * 768 + 256 + h * 32 + scol4);
    *(float4*)KB4(kb, r, scol4) = v;
  }
  __syncthreads();

  // ---- Phase 1: scores + inline softmax. thread = 8q (qgw+4r) x 8k.
  {
    const int qgw = t >> 6;            // wave id: wave-uniform q group
    const int kg  = t & 63;            // k cols kg*4..+3 and 256+kg*4..+3
    float s8[8][8] = {};
#pragma unroll 2
    for (int kk = 0; kk < 32; kk += 4) {
      float4 qf[8], kf1[4], kf2[4];
#pragma unroll
      for (int r = 0; r < 8; ++r) qf[r] = *(const float4*)&qs[qgw + 4 * r][kk];
#pragma unroll
      for (int c = 0; c < 4; ++c) {
        kf1[c] = *(const float4*)KB4(kb, kg * 4 + c, kk);
        kf2[c] = *(const float4*)KB4(kb, 256 + kg * 4 + c, kk);
      }
#pragma unroll
      for (int r = 0; r < 8; ++r)
#pragma unroll
        for (int c = 0; c < 4; ++c) {
          s8[r][c]     += qf[r].x * kf1[c].x + qf[r].y * kf1[c].y +
                          qf[r].z * kf1[c].z + qf[r].w * kf1[c].w;
          s8[r][4 + c] += qf[r].x * kf2[c].x + qf[r].y * kf2[c].y +
                          qf[r].z * kf2[c].z + qf[r].w * kf2[c].w;
        }
    }
    // exp in registers + per-row local sums
    float rs[8];
#pragma unroll
    for (int r = 0; r < 8; ++r) {
      float s = 0.f;
#pragma unroll
      for (int c = 0; c < 8; ++c) {
        s8[r][c] = __expf(s8[r][c]);
        s += s8[r][c];
      }
      rs[r] = s;
    }
    // wave butterfly: full row sums (row qgw+4r owned entirely by wave qgw)
#pragma unroll
    for (int m = 1; m < 64; m <<= 1)
#pragma unroll
      for (int r = 0; r < 8; ++r) rs[r] += __shfl_xor(rs[r], m);
    if ((t & 63) == 0)
#pragma unroll
      for (int r = 0; r < 8; ++r) red[qgw + 4 * r] = rs[r];
    // write unnormalized e
#pragma unroll
    for (int r = 0; r < 8; ++r) {
      const int rq = qgw + 4 * r;
      *(float4*)&sc[rq * 516 + kg * 4] =
          make_float4(s8[r][0], s8[r][1], s8[r][2], s8[r][3]);
      *(float4*)&sc[rq * 516 + 256 + kg * 4] =
          make_float4(s8[r][4], s8[r][5], s8[r][6], s8[r][7]);
    }
  }
  __syncthreads();                     // sc/red done; kb K-reads done

  // ---- stage FULL VP panel into kb
#pragma unroll 8
  for (int u = 0; u < 16; ++u) {
    const int r = srow + 32 * u;
    float4 v = *(const float4*)(vp + ((size_t)(b * 512 + r)) * 256 + h * 32 + scol4);
    *(float4*)KB4(kb, r, scol4) = v;
  }
  __syncthreads();

  // ---- Phase 3: ACC[q][a] = sum_k e[q][k]*vp[k][a]; thread = 8q x 4a,
  // 8-way k-split (64 k per slice).
  const int ag  = t & 7;               // a cols ag*4..+3
  const int qg3 = (t >> 3) & 3;        // q rows qg3+4r
  const int ks  = t >> 5;              // 0..7
  float a3[8][4] = {};
#pragma unroll 2
  for (int g = 0; g < 16; ++g) {
    const int kbase = ks * 64 + g * 4;
    float4 sq[8], vf[4];
#pragma unroll
    for (int r = 0; r < 8; ++r)
      sq[r] = *(const float4*)&sc[(qg3 + 4 * r) * 516 + kbase];
#pragma unroll
    for (int c = 0; c < 4; ++c)
      vf[c] = *(const float4*)KB4(kb, kbase + c, ag * 4);
#pragma unroll
    for (int r = 0; r < 8; ++r) {
      a3[r][0] += sq[r].x * vf[0].x + sq[r].y * vf[1].x + sq[r].z * vf[2].x + sq[r].w * vf[3].x;
      a3[r][1] += sq[r].x * vf[0].y + sq[r].y * vf[1].y + sq[r].z * vf[2].y + sq[r].w * vf[3].y;
      a3[r][2] += sq[r].x * vf[0].z + sq[r].y * vf[1].z + sq[r].z * vf[2].z + sq[r].w * vf[3].z;
      a3[r][3] += sq[r].x * vf[0].w + sq[r].y * vf[1].w + sq[r].z * vf[2].w + sq[r].w * vf[3].w;
    }
  }

  // ---- fold ks pair within wave (wave w holds ks = 2w, 2w+1)
#pragma unroll
  for (int r = 0; r < 8; ++r)
#pragma unroll
    for (int c = 0; c < 4; ++c)
      a3[r][c] += __shfl_xor(a3[r][c], 32);
  __syncthreads();                     // kb reads done; reuse as part
  float* part = &kb[0];                // [w4][32*36]
  if ((t & 32) == 0) {
    const int w = t >> 6;
#pragma unroll
    for (int r = 0; r < 8; ++r)
#pragma unroll
      for (int c = 0; c < 4; ++c)
        part[w * 1152 + (qg3 + 4 * r) * 36 + ag * 4 + c] = a3[r][c];
  }
  __syncthreads();

  // ---- final 4-wave reduction + robust power-mean epilogue (4 outputs/thr)
  {
    const int q = t >> 3, a0 = (t & 7) << 2;
    const int d0 = h * 32 + a0;
    const float invT = 1.0f / red[q];
    float4 s0 = *(const float4*)&part[q * 36 + a0];
    float4 s1 = *(const float4*)&part[1152 + q * 36 + a0];
    float4 s2 = *(const float4*)&part[2304 + q * 36 + a0];
    float4 s3 = *(const float4*)&part[3456 + q * 36 + a0];
    const float4 pp = *(const float4*)(pw + d0);
    const float4 vr = *(const float4*)(vrangew + b * 256 + d0);
    const float4 vm = *(const float4*)(vminw + b * 256 + d0);
    float4 o;
    o.x = (expf(log1pf((s0.x + s1.x + s2.x + s3.x) * invT) / pp.x) - BCONST) * vr.x / ONE_MINUS_B + vm.x;
    o.y = (expf(log1pf((s0.y + s1.y + s2.y + s3.y) * invT) / pp.y) - BCONST) * vr.y / ONE_MINUS_B + vm.y;
    o.z = (expf(log1pf((s0.z + s1.z + s2.z + s3.z) * invT) / pp.z) - BCONST) * vr.z / ONE_MINUS_B + vm.z;
    o.w = (expf(log1pf((s0.w + s1.w + s2.w + s3.w) * invT) / pp.w) - BCONST) * vr.w / ONE_MINUS_B + vm.w;
    *(float4*)(ew + ((size_t)(b * 512 + q0g + q)) * 256 + d0) = o;
  }
}

// ---------------------------------------------------------------------------
extern "C" void kernel_launch(void* const* d_in, const int* in_sizes, int n_in,
                              void* d_out, int out_size, void* d_ws, size_t ws_size,
                              hipStream_t stream) {
  const float* ctx  = (const float*)d_in[0];
  const float* WQ   = (const float*)d_in[1];
  const float* WKV  = (const float*)d_in[2];
  const float* WOUT = (const float*)d_in[3];
  const float* PP   = (const float*)d_in[4];
  float* ws      = (float*)d_ws;
  float* qkv     = ws + OFF_QKV;
  float* vp      = ws + OFF_VP;
  float* ew      = ws + OFF_EW;
  float* pminP   = ws + OFF_PMIN;
  float* pmaxP   = ws + OFF_PMAX;
  float* vminw   = ws + OFF_VMIN;
  float* vrangew = ws + OFF_VRANGE;
  float* pw      = ws + OFF_P;
  float* out     = (float*)d_out;

  // Fused Q|K|V projection + V min/max partials: 1024x768x256, 32x64 tiles
  gemm_t<32, 64, 2, 4, true><<<dim3(32, 12), 256, 0, stream>>>(
      ctx, WQ, WKV, 256, qkv, 768, 256, 256, pminP, pmaxP);
  // expm1(p * log(v_norm)) + p vector + vmin/vrange (16 partials/batch)
  vpk<<<1024, 256, 0, stream>>>(qkv, pminP, pmaxP, PP, vp, vminw, vrangew, pw);
  // Fused attention + inline softmax + power-mean epilogue
  attn_k<<<dim3(16, 16), 256, 0, stream>>>(qkv, vp, pw, vminw, vrangew, ew);
  // Output projection: 1024x256x256, 32x32 tiles (256 blocks)
  gemm_t<32, 32, 2, 2, false><<<dim3(32, 8), 256, 0, stream>>>(
      ew, WOUT, WOUT, 1 << 30, out, 256, 256, 256, nullptr, nullptr);
}